// Round 3
// baseline (12838.777 us; speedup 1.0000x reference)
//
#include <hip/hip_runtime.h>
#include <math.h>

// ---------------------------------------------------------------------------
// NCPDecoder: 3-cell CfC RNN, B=1024, T=256.
// Round 2: mask-dtype fix. R1/R2 produced bit-identical absmax 3.8e-2 under
// f32 vs f64 accumulation => dynamics are contractive and the error is a
// deterministic bug. Prime suspect: bool masks uploaded as int32, read here
// as bytes. prep_kernel now runtime-detects the mask element width (uint8 /
// int32 / f32) via the structurally all-ones h-block. Matvec back to f32
// accumulation (A/B proved precision-insensitive).
// ---------------------------------------------------------------------------

namespace {
constexpr int kBatch = 1024;
constexpr int kT     = 256;
constexpr int kDIN   = 128;
constexpr int kUNITS = 512;
constexpr int kINTER = 269;
constexpr int kCMD   = 179;
constexpr int kMOTOR = 64;
constexpr int kOUT   = 64;

constexpr int kC0 = 3 * kINTER;  // 807 combined cols (ff1|ff2|t)
constexpr int kC1 = 3 * kCMD;    // 537
constexpr int kC2 = 3 * kMOTOR;  // 192
constexpr int kCAT0 = kDIN + kINTER;    // 397
constexpr int kCAT1 = kINTER + kCMD;    // 448
constexpr int kCAT2 = kCMD + kMOTOR;    // 243
constexpr int kK40 = (kCAT0 + 3) / 4;   // 100
constexpr int kK41 = (kCAT1 + 3) / 4;   // 112
constexpr int kK42 = (kCAT2 + 3) / 4;   // 61
constexpr int kS0 = kK40 * 4;           // 400 (padded cat, LDS stride)
constexpr int kS1 = kK41 * 4;           // 448
constexpr int kS2 = kK42 * 4;           // 244

constexpr int kQ0 = kK40 * kC0;         // 80700 float4 quads
constexpr int kQ1 = kK41 * kC1;         // 60144
constexpr int kQ2 = kK42 * kC2;         // 11712
constexpr int kQ  = kQ0 + kQ1 + kQ2;    // 152556
constexpr int kBCN = kC0 + kC1 + kC2;   // 1536 fused biases

// offsets inside workspace
constexpr int kW1OffQ = kQ0;            // in float4 units
constexpr int kW2OffQ = kQ0 + kQ1;
constexpr int kBCOff  = kQ * 4;         // in float units

constexpr int kMT = 4;    // batch rows per WG
constexpr int kNT = 512;  // threads per WG
constexpr int kPS = 832;  // pacc LDS stride (>= kC0)
}  // namespace

// Mask element-width detection. mask0 row 0, columns 128..396 are the
// structurally all-true h-block (full = concat([m, ones(n_h,n_h)]) then .T).
//  - uint8 layout: bytes 128..143 are 1 -> words 32..35 == 0x01010101
//  - f32   layout: elements 128..130 are 1.0f -> words 128..130 == 0x3F800000
//  - else: int32 (elements are 0/1 words; can't match either pattern)
__device__ __forceinline__ int detect_mask_mode(const void* m0) {
  const unsigned int* w = (const unsigned int*)m0;
  if (w[32] == 0x01010101u && w[33] == 0x01010101u &&
      w[34] == 0x01010101u && w[35] == 0x01010101u)
    return 0;  // uint8
  if (w[128] == 0x3F800000u && w[129] == 0x3F800000u && w[130] == 0x3F800000u)
    return 2;  // f32
  return 1;    // int32
}

__device__ __forceinline__ bool mask_at(const void* mk, int idx, int mode) {
  if (mode == 0) return ((const unsigned char*)mk)[idx] != 0;
  if (mode == 1) return ((const int*)mk)[idx] != 0;
  return ((const float*)mk)[idx] != 0.0f;
}

// ---------------------------------------------------------------------------
// Prep: build packed masked/fused weights in workspace.
// Layout: W[cell][k/4][col][4] float4 quads; fused ta+tb (ts==1.0); biases.
// ---------------------------------------------------------------------------
__global__ void prep_kernel(
    const void* __restrict__ m0_, const void* __restrict__ m1_,
    const void* __restrict__ m2_,
    const float* __restrict__ f1w0, const float* __restrict__ f2w0,
    const float* __restrict__ taw0, const float* __restrict__ tbw0,
    const float* __restrict__ f1w1, const float* __restrict__ f2w1,
    const float* __restrict__ taw1, const float* __restrict__ tbw1,
    const float* __restrict__ f1w2, const float* __restrict__ f2w2,
    const float* __restrict__ taw2, const float* __restrict__ tbw2,
    const float* __restrict__ f1b0, const float* __restrict__ f2b0,
    const float* __restrict__ tab0, const float* __restrict__ tbb0,
    const float* __restrict__ f1b1, const float* __restrict__ f2b1,
    const float* __restrict__ tab1, const float* __restrict__ tbb1,
    const float* __restrict__ f1b2, const float* __restrict__ f2b2,
    const float* __restrict__ tab2, const float* __restrict__ tbb2,
    float* __restrict__ ws) {
  int i = blockIdx.x * 256 + threadIdx.x;
  const int mode = detect_mask_mode(m0_);
  if (i < kQ) {
    int qi, ncols, cat, nh, baseq;
    const void* mk;
    const float *wf1, *wf2, *wta, *wtb;
    if (i < kQ0) {
      qi = i; ncols = kC0; cat = kCAT0; nh = kINTER; mk = m0_;
      wf1 = f1w0; wf2 = f2w0; wta = taw0; wtb = tbw0; baseq = 0;
    } else if (i < kQ0 + kQ1) {
      qi = i - kQ0; ncols = kC1; cat = kCAT1; nh = kCMD; mk = m1_;
      wf1 = f1w1; wf2 = f2w1; wta = taw1; wtb = tbw1; baseq = kW1OffQ;
    } else {
      qi = i - kQ0 - kQ1; ncols = kC2; cat = kCAT2; nh = kMOTOR; mk = m2_;
      wf1 = f1w2; wf2 = f2w2; wta = taw2; wtb = tbw2; baseq = kW2OffQ;
    }
    int k4 = qi / ncols;
    int j  = qi % ncols;
    float v[4];
#pragma unroll
    for (int kk = 0; kk < 4; ++kk) {
      int k = k4 * 4 + kk;
      float r = 0.0f;
      if (k < cat) {
        if (j < nh) {
          r = mask_at(mk, j * cat + k, mode) ? wf1[j * cat + k] : 0.0f;
        } else if (j < 2 * nh) {
          int jj = j - nh;
          r = mask_at(mk, jj * cat + k, mode) ? wf2[jj * cat + k] : 0.0f;
        } else {
          int jj = j - 2 * nh;
          r = wta[jj * cat + k] + wtb[jj * cat + k];
        }
      }
      v[kk] = r;
    }
    float4* dst = (float4*)ws;
    dst[baseq + qi] = make_float4(v[0], v[1], v[2], v[3]);
  } else if (i < kQ + kBCN) {
    int pos = i - kQ;
    int j = pos, nh;
    const float *bf1, *bf2, *bta, *btb;
    if (j < kC0) {
      nh = kINTER; bf1 = f1b0; bf2 = f2b0; bta = tab0; btb = tbb0;
    } else if (j < kC0 + kC1) {
      j -= kC0; nh = kCMD; bf1 = f1b1; bf2 = f2b1; bta = tab1; btb = tbb1;
    } else {
      j -= kC0 + kC1; nh = kMOTOR; bf1 = f1b2; bf2 = f2b2; bta = tab2; btb = tbb2;
    }
    float r;
    if (j < nh) r = bf1[j];
    else if (j < 2 * nh) r = bf2[j - nh];
    else r = bta[j - 2 * nh] + btb[j - 2 * nh];
    ws[kBCOff + pos] = r;
  }
}

// ---------------------------------------------------------------------------
// Batched (kMT rows) mat-vec over combined columns; thread owns col j0 (and
// j0+512 if DUAL). A is LDS f32 (broadcast reads), W streams from L2 as
// float4, f32 FMA accumulation (precision-insensitivity proven R1 vs R2).
// ---------------------------------------------------------------------------
template <bool DUAL, int ASTRIDE>
__device__ __forceinline__ void cell_matmul(const float4* __restrict__ wp,
                                            int ncols, int nk4,
                                            const float* __restrict__ a,
                                            float* __restrict__ pc,
                                            int j0, int j1) {
  float acc0[kMT], acc1[kMT];
#pragma unroll
  for (int r = 0; r < kMT; ++r) { acc0[r] = 0.0f; acc1[r] = 0.0f; }
  const float4* p0 = wp + j0;
  const float4* p1 = wp + j1;
  for (int k4 = 0; k4 < nk4; ++k4) {
    float4 w0 = *p0; p0 += ncols;
    float4 w1;
    if (DUAL) { w1 = *p1; p1 += ncols; }
    const float* ak = a + (k4 << 2);
#pragma unroll
    for (int r = 0; r < kMT; ++r) {
      float4 av = *(const float4*)(ak + r * ASTRIDE);
      acc0[r] = fmaf(w0.x, av.x, acc0[r]);
      acc0[r] = fmaf(w0.y, av.y, acc0[r]);
      acc0[r] = fmaf(w0.z, av.z, acc0[r]);
      acc0[r] = fmaf(w0.w, av.w, acc0[r]);
      if (DUAL) {
        acc1[r] = fmaf(w1.x, av.x, acc1[r]);
        acc1[r] = fmaf(w1.y, av.y, acc1[r]);
        acc1[r] = fmaf(w1.z, av.z, acc1[r]);
        acc1[r] = fmaf(w1.w, av.w, acc1[r]);
      }
    }
  }
#pragma unroll
  for (int r = 0; r < kMT; ++r) {
    pc[r * kPS + j0] = acc0[r];
    if (DUAL) pc[r * kPS + j1] = acc1[r];
  }
}

__device__ __forceinline__ float cfc_combine(float p1, float p2, float pt) {
  float f1 = tanhf(p1);
  float f2 = tanhf(p2);
  float ti = 1.0f / (1.0f + expf(-pt));
  return f1 + ti * (f2 - f1);
}

// ---------------------------------------------------------------------------
// Main persistent RNN kernel: one WG per kMT batch rows, loops over T steps.
// ---------------------------------------------------------------------------
__global__ __launch_bounds__(kNT) void ncp_main(
    const float* __restrict__ x, const float* __restrict__ hidden,
    const float* __restrict__ ws, const float* __restrict__ fcw,
    const float* __restrict__ fcb, float* __restrict__ out) {
  __shared__ __align__(16) float xc0[kMT][kS0];   // [x_t | h0 | pad]
  __shared__ __align__(16) float xc1[kMT][kS1];   // [n0  | h1]
  __shared__ __align__(16) float xc2[kMT][kS2];   // [n1  | h2 | pad]
  __shared__ __align__(16) float pacc[kMT][kPS];  // pre-activation exchange
  __shared__ float s_fcwT[64 * 64];               // fc_w transposed [m][o]
  __shared__ float s_bc[kBCN];
  __shared__ float s_fcb[64];

  const int tid = threadIdx.x;
  const int b0 = blockIdx.x * kMT;

  // zero xc buffers (covers the k-padding lanes; padded W entries are zero
  // but 0*garbage(NaN) would still poison accumulators)
#pragma unroll
  for (int r = 0; r < kMT; ++r) {
    if (tid < kS0) xc0[r][tid] = 0.0f;
    if (tid < kS1) xc1[r][tid] = 0.0f;
    if (tid < kS2) xc2[r][tid] = 0.0f;
  }
  __syncthreads();
  // initial hidden state -> h slots
  for (int i = tid; i < kMT * kUNITS; i += kNT) {
    int r = i >> 9, u = i & 511;
    float v = hidden[(size_t)(b0 + r) * kUNITS + u];
    if (u < kINTER) xc0[r][kDIN + u] = v;
    else if (u < kINTER + kCMD) xc1[r][u] = v;  // layout offset == u
    else xc2[r][kCMD + (u - (kINTER + kCMD))] = v;
  }
  for (int i = tid; i < kBCN; i += kNT) s_bc[i] = ws[kBCOff + i];
  if (tid < 64) s_fcb[tid] = fcb[tid];
  for (int i = tid; i < 64 * 64; i += kNT) {
    int m = i >> 6, o = i & 63;
    s_fcwT[i] = fcw[o * 64 + m];
  }
  __syncthreads();

  const float4* wp0 = (const float4*)ws;
  const float4* wp1 = (const float4*)ws + kW1OffQ;
  const float4* wp2 = (const float4*)ws + kW2OffQ;

  for (int t = 0; t < kT; ++t) {
    // stage x_t (one element per thread: kMT*kDIN == 512)
    {
      int r = tid >> 7, d = tid & 127;
      xc0[r][d] = x[(size_t)(b0 + r) * (kT * kDIN) + t * kDIN + d];
    }
    __syncthreads();

    // ---- cell 0 ----
    if (tid < kC0 - kNT)
      cell_matmul<true, kS0>(wp0, kC0, kK40, &xc0[0][0], &pacc[0][0], tid, tid + kNT);
    else
      cell_matmul<false, kS0>(wp0, kC0, kK40, &xc0[0][0], &pacc[0][0], tid, 0);
    __syncthreads();
    if (tid < kINTER) {
#pragma unroll
      for (int r = 0; r < kMT; ++r) {
        float v = cfc_combine(pacc[r][tid] + s_bc[tid],
                              pacc[r][tid + kINTER] + s_bc[tid + kINTER],
                              pacc[r][tid + 2 * kINTER] + s_bc[tid + 2 * kINTER]);
        xc1[r][tid] = v;          // input to cell 1
        xc0[r][kDIN + tid] = v;   // h0 for next step
      }
    }
    __syncthreads();

    // ---- cell 1 ----
    if (tid < kC1 - kNT)
      cell_matmul<true, kS1>(wp1, kC1, kK41, &xc1[0][0], &pacc[0][0], tid, tid + kNT);
    else
      cell_matmul<false, kS1>(wp1, kC1, kK41, &xc1[0][0], &pacc[0][0], tid, 0);
    __syncthreads();
    if (tid < kCMD) {
#pragma unroll
      for (int r = 0; r < kMT; ++r) {
        float v = cfc_combine(pacc[r][tid] + s_bc[kC0 + tid],
                              pacc[r][tid + kCMD] + s_bc[kC0 + tid + kCMD],
                              pacc[r][tid + 2 * kCMD] + s_bc[kC0 + tid + 2 * kCMD]);
        xc2[r][tid] = v;          // input to cell 2
        xc1[r][kINTER + tid] = v; // h1
      }
    }
    __syncthreads();

    // ---- cell 2 ----
    if (tid < kC2)
      cell_matmul<false, kS2>(wp2, kC2, kK42, &xc2[0][0], &pacc[0][0], tid, 0);
    __syncthreads();
    if (tid < kMOTOR) {
#pragma unroll
      for (int r = 0; r < kMT; ++r) {
        float v = cfc_combine(pacc[r][tid] + s_bc[kC0 + kC1 + tid],
                              pacc[r][tid + kMOTOR] + s_bc[kC0 + kC1 + tid + kMOTOR],
                              pacc[r][tid + 2 * kMOTOR] + s_bc[kC0 + kC1 + tid + 2 * kMOTOR]);
        xc2[r][kCMD + tid] = v;   // h2 == n2 == outs[t]
      }
    }
    __syncthreads();

    // ---- fc head: pred[b,t,o] = sum_m n2[m] * fc_w[o,m] + fc_b[o] ----
    {
      int r = tid >> 6, o = tid & 63;
      if (r < kMT) {
        float acc = s_fcb[o];
#pragma unroll
        for (int m = 0; m < kMOTOR; ++m)
          acc = fmaf(xc2[r][kCMD + m], s_fcwT[m * 64 + o], acc);
        out[(size_t)(b0 + r) * (kT * kOUT) + (size_t)t * kOUT + o] = acc;
      }
    }
    // next-iter x staging touches only xc0[:, :128]; no reader remains -> no
    // trailing barrier needed (loop-top barrier orders staging vs matmul0).
  }
  __syncthreads();

  // final hidden state
  const size_t hnoff = (size_t)kBatch * kT * kOUT;
  for (int i = tid; i < kMT * kUNITS; i += kNT) {
    int r = i >> 9, u = i & 511;
    float v;
    if (u < kINTER) v = xc0[r][kDIN + u];
    else if (u < kINTER + kCMD) v = xc1[r][u];
    else v = xc2[r][kCMD + (u - (kINTER + kCMD))];
    out[hnoff + (size_t)(b0 + r) * kUNITS + u] = v;
  }
}

// ---------------------------------------------------------------------------
extern "C" void kernel_launch(void* const* d_in, const int* in_sizes, int n_in,
                              void* d_out, int out_size, void* d_ws, size_t ws_size,
                              hipStream_t stream) {
  (void)in_sizes; (void)n_in; (void)out_size; (void)ws_size;
  const float* x = (const float*)d_in[0];
  const float* hidden = (const float*)d_in[1];
  const void* m0 = d_in[2];
  const void* m1 = d_in[3];
  const void* m2 = d_in[4];
  // layer li block: ff1_w, ff1_b, ff2_w, ff2_b, ta_w, ta_b, tb_w, tb_b
  const float* f1w0 = (const float*)d_in[5];
  const float* f1b0 = (const float*)d_in[6];
  const float* f2w0 = (const float*)d_in[7];
  const float* f2b0 = (const float*)d_in[8];
  const float* taw0 = (const float*)d_in[9];
  const float* tab0 = (const float*)d_in[10];
  const float* tbw0 = (const float*)d_in[11];
  const float* tbb0 = (const float*)d_in[12];
  const float* f1w1 = (const float*)d_in[13];
  const float* f1b1 = (const float*)d_in[14];
  const float* f2w1 = (const float*)d_in[15];
  const float* f2b1 = (const float*)d_in[16];
  const float* taw1 = (const float*)d_in[17];
  const float* tab1 = (const float*)d_in[18];
  const float* tbw1 = (const float*)d_in[19];
  const float* tbb1 = (const float*)d_in[20];
  const float* f1w2 = (const float*)d_in[21];
  const float* f1b2 = (const float*)d_in[22];
  const float* f2w2 = (const float*)d_in[23];
  const float* f2b2 = (const float*)d_in[24];
  const float* taw2 = (const float*)d_in[25];
  const float* tab2 = (const float*)d_in[26];
  const float* tbw2 = (const float*)d_in[27];
  const float* tbb2 = (const float*)d_in[28];
  const float* fcw = (const float*)d_in[29];
  const float* fcb = (const float*)d_in[30];
  float* ws = (float*)d_ws;
  float* out = (float*)d_out;

  const int prep_items = kQ + kBCN;  // 154092
  prep_kernel<<<(prep_items + 255) / 256, 256, 0, stream>>>(
      m0, m1, m2,
      f1w0, f2w0, taw0, tbw0,
      f1w1, f2w1, taw1, tbw1,
      f1w2, f2w2, taw2, tbw2,
      f1b0, f2b0, tab0, tbb0,
      f1b1, f2b1, tab1, tbb1,
      f1b2, f2b2, tab2, tbb2,
      ws);

  ncp_main<<<kBatch / kMT, kNT, 0, stream>>>(x, hidden, ws, fcw, fcb, out);
}

// Round 4
// 10113.534 us; speedup vs baseline: 1.2695x; 1.2695x over previous
//
#include <hip/hip_runtime.h>
#include <math.h>

// ---------------------------------------------------------------------------
// NCPDecoder: 3-cell CfC RNN, B=1024, T=256.
// Round 3->4: occupancy + balance. R3 passed at 12.8 ms with VALUBusy 48%,
// Occupancy 24% (1 WG/CU, 2 waves/SIMD) — latency-bound on the L2 weight
// stream, plus 63% column imbalance from the DUAL split. This round: 1024
// threads/WG (16 waves/CU), ONE column per thread (critical path 273 vs 485
// k4-units), compile-time shapes, register prefetch of the next weight quad,
// bias folded into accumulator init. Grid stays 256 (weight traffic fixed).
// ---------------------------------------------------------------------------

namespace {
constexpr int kBatch = 1024;
constexpr int kT     = 256;
constexpr int kDIN   = 128;
constexpr int kUNITS = 512;
constexpr int kINTER = 269;
constexpr int kCMD   = 179;
constexpr int kMOTOR = 64;
constexpr int kOUT   = 64;

constexpr int kC0 = 3 * kINTER;  // 807 combined cols (ff1|ff2|t)
constexpr int kC1 = 3 * kCMD;    // 537
constexpr int kC2 = 3 * kMOTOR;  // 192
constexpr int kCAT0 = kDIN + kINTER;    // 397
constexpr int kCAT1 = kINTER + kCMD;    // 448
constexpr int kCAT2 = kCMD + kMOTOR;    // 243
constexpr int kK40 = (kCAT0 + 3) / 4;   // 100
constexpr int kK41 = (kCAT1 + 3) / 4;   // 112
constexpr int kK42 = (kCAT2 + 3) / 4;   // 61
constexpr int kS0 = kK40 * 4;           // 400 (padded cat, LDS stride)
constexpr int kS1 = kK41 * 4;           // 448
constexpr int kS2 = kK42 * 4;           // 244

constexpr int kQ0 = kK40 * kC0;         // 80700 float4 quads
constexpr int kQ1 = kK41 * kC1;         // 60144
constexpr int kQ2 = kK42 * kC2;         // 11712
constexpr int kQ  = kQ0 + kQ1 + kQ2;    // 152556
constexpr int kBCN = kC0 + kC1 + kC2;   // 1536 fused biases

// offsets inside workspace
constexpr int kW1OffQ = kQ0;            // in float4 units
constexpr int kW2OffQ = kQ0 + kQ1;
constexpr int kBCOff  = kQ * 4;         // in float units

constexpr int kMT = 4;     // batch rows per WG
constexpr int kNT = 1024;  // threads per WG (16 waves -> 4/SIMD)
constexpr int kPS = 832;   // pacc LDS stride (>= kC0)
}  // namespace

// Mask element-width detection. mask0 row 0, columns 128..396 are the
// structurally all-true h-block (full = concat([m, ones(n_h,n_h)]) then .T).
__device__ __forceinline__ int detect_mask_mode(const void* m0) {
  const unsigned int* w = (const unsigned int*)m0;
  if (w[32] == 0x01010101u && w[33] == 0x01010101u &&
      w[34] == 0x01010101u && w[35] == 0x01010101u)
    return 0;  // uint8
  if (w[128] == 0x3F800000u && w[129] == 0x3F800000u && w[130] == 0x3F800000u)
    return 2;  // f32
  return 1;    // int32
}

__device__ __forceinline__ bool mask_at(const void* mk, int idx, int mode) {
  if (mode == 0) return ((const unsigned char*)mk)[idx] != 0;
  if (mode == 1) return ((const int*)mk)[idx] != 0;
  return ((const float*)mk)[idx] != 0.0f;
}

// ---------------------------------------------------------------------------
// Prep: build packed masked/fused weights in workspace.
// Layout: W[cell][k/4][col][4] float4 quads; fused ta+tb (ts==1.0); biases.
// ---------------------------------------------------------------------------
__global__ void prep_kernel(
    const void* __restrict__ m0_, const void* __restrict__ m1_,
    const void* __restrict__ m2_,
    const float* __restrict__ f1w0, const float* __restrict__ f2w0,
    const float* __restrict__ taw0, const float* __restrict__ tbw0,
    const float* __restrict__ f1w1, const float* __restrict__ f2w1,
    const float* __restrict__ taw1, const float* __restrict__ tbw1,
    const float* __restrict__ f1w2, const float* __restrict__ f2w2,
    const float* __restrict__ taw2, const float* __restrict__ tbw2,
    const float* __restrict__ f1b0, const float* __restrict__ f2b0,
    const float* __restrict__ tab0, const float* __restrict__ tbb0,
    const float* __restrict__ f1b1, const float* __restrict__ f2b1,
    const float* __restrict__ tab1, const float* __restrict__ tbb1,
    const float* __restrict__ f1b2, const float* __restrict__ f2b2,
    const float* __restrict__ tab2, const float* __restrict__ tbb2,
    float* __restrict__ ws) {
  int i = blockIdx.x * 256 + threadIdx.x;
  const int mode = detect_mask_mode(m0_);
  if (i < kQ) {
    int qi, ncols, cat, nh, baseq;
    const void* mk;
    const float *wf1, *wf2, *wta, *wtb;
    if (i < kQ0) {
      qi = i; ncols = kC0; cat = kCAT0; nh = kINTER; mk = m0_;
      wf1 = f1w0; wf2 = f2w0; wta = taw0; wtb = tbw0; baseq = 0;
    } else if (i < kQ0 + kQ1) {
      qi = i - kQ0; ncols = kC1; cat = kCAT1; nh = kCMD; mk = m1_;
      wf1 = f1w1; wf2 = f2w1; wta = taw1; wtb = tbw1; baseq = kW1OffQ;
    } else {
      qi = i - kQ0 - kQ1; ncols = kC2; cat = kCAT2; nh = kMOTOR; mk = m2_;
      wf1 = f1w2; wf2 = f2w2; wta = taw2; wtb = tbw2; baseq = kW2OffQ;
    }
    int k4 = qi / ncols;
    int j  = qi % ncols;
    float v[4];
#pragma unroll
    for (int kk = 0; kk < 4; ++kk) {
      int k = k4 * 4 + kk;
      float r = 0.0f;
      if (k < cat) {
        if (j < nh) {
          r = mask_at(mk, j * cat + k, mode) ? wf1[j * cat + k] : 0.0f;
        } else if (j < 2 * nh) {
          int jj = j - nh;
          r = mask_at(mk, jj * cat + k, mode) ? wf2[jj * cat + k] : 0.0f;
        } else {
          int jj = j - 2 * nh;
          r = wta[jj * cat + k] + wtb[jj * cat + k];
        }
      }
      v[kk] = r;
    }
    float4* dst = (float4*)ws;
    dst[baseq + qi] = make_float4(v[0], v[1], v[2], v[3]);
  } else if (i < kQ + kBCN) {
    int pos = i - kQ;
    int j = pos, nh;
    const float *bf1, *bf2, *bta, *btb;
    if (j < kC0) {
      nh = kINTER; bf1 = f1b0; bf2 = f2b0; bta = tab0; btb = tbb0;
    } else if (j < kC0 + kC1) {
      j -= kC0; nh = kCMD; bf1 = f1b1; bf2 = f2b1; bta = tab1; btb = tbb1;
    } else {
      j -= kC0 + kC1; nh = kMOTOR; bf1 = f1b2; bf2 = f2b2; bta = tab2; btb = tbb2;
    }
    float r;
    if (j < nh) r = bf1[j];
    else if (j < 2 * nh) r = bf2[j - nh];
    else r = bta[j - 2 * nh] + btb[j - 2 * nh];
    ws[kBCOff + pos] = r;
  }
}

// ---------------------------------------------------------------------------
// One column per thread, kMT rows, compile-time shapes. Bias folded into the
// accumulator init; next weight quad prefetched into registers to put one
// iteration of FMA work between the L2 load and its use.
// ---------------------------------------------------------------------------
template <int NCOLS, int NK4, int ASTRIDE>
__device__ __forceinline__ void cell_matvec(const float4* __restrict__ wp,
                                            const float* __restrict__ a,
                                            float* __restrict__ pc,
                                            const float* __restrict__ bias,
                                            int j) {
  float acc[kMT];
  const float b = bias[j];
#pragma unroll
  for (int r = 0; r < kMT; ++r) acc[r] = b;
  const float4* p = wp + j;
  float4 w = *p;
  const float* ak = a;
  for (int k4 = 0; k4 < NK4 - 1; ++k4) {
    float4 wn = p[(k4 + 1) * NCOLS];  // prefetch next quad (L2)
#pragma unroll
    for (int r = 0; r < kMT; ++r) {
      float4 av = *(const float4*)(ak + r * ASTRIDE);
      acc[r] = fmaf(w.x, av.x, acc[r]);
      acc[r] = fmaf(w.y, av.y, acc[r]);
      acc[r] = fmaf(w.z, av.z, acc[r]);
      acc[r] = fmaf(w.w, av.w, acc[r]);
    }
    ak += 4;
    w = wn;
  }
#pragma unroll
  for (int r = 0; r < kMT; ++r) {
    float4 av = *(const float4*)(ak + r * ASTRIDE);
    acc[r] = fmaf(w.x, av.x, acc[r]);
    acc[r] = fmaf(w.y, av.y, acc[r]);
    acc[r] = fmaf(w.z, av.z, acc[r]);
    acc[r] = fmaf(w.w, av.w, acc[r]);
  }
#pragma unroll
  for (int r = 0; r < kMT; ++r) pc[r * kPS + j] = acc[r];
}

__device__ __forceinline__ float cfc_combine(float p1, float p2, float pt) {
  float f1 = tanhf(p1);
  float f2 = tanhf(p2);
  float ti = 1.0f / (1.0f + expf(-pt));
  return f1 + ti * (f2 - f1);
}

// ---------------------------------------------------------------------------
// Main persistent RNN kernel: one WG per kMT batch rows, loops over T steps.
// ---------------------------------------------------------------------------
__global__ __launch_bounds__(kNT) void ncp_main(
    const float* __restrict__ x, const float* __restrict__ hidden,
    const float* __restrict__ ws, const float* __restrict__ fcw,
    const float* __restrict__ fcb, float* __restrict__ out) {
  __shared__ __align__(16) float xc0[kMT][kS0];   // [x_t | h0 | pad]
  __shared__ __align__(16) float xc1[kMT][kS1];   // [n0  | h1]
  __shared__ __align__(16) float xc2[kMT][kS2];   // [n1  | h2 | pad]
  __shared__ __align__(16) float pacc[kMT][kPS];  // pre-act (bias included)
  __shared__ float s_fcwT[64 * 64];               // fc_w transposed [m][o]
  __shared__ float s_bc[kBCN];
  __shared__ float s_fcb[64];

  const int tid = threadIdx.x;
  const int b0 = blockIdx.x * kMT;

  // zero xc buffers (covers k-padding lanes: padded W entries are zero but
  // 0*garbage(NaN) would still poison accumulators)
#pragma unroll
  for (int r = 0; r < kMT; ++r) {
    if (tid < kS0) xc0[r][tid] = 0.0f;
    if (tid < kS1) xc1[r][tid] = 0.0f;
    if (tid < kS2) xc2[r][tid] = 0.0f;
  }
  __syncthreads();
  // initial hidden state -> h slots
  for (int i = tid; i < kMT * kUNITS; i += kNT) {
    int r = i >> 9, u = i & 511;
    float v = hidden[(size_t)(b0 + r) * kUNITS + u];
    if (u < kINTER) xc0[r][kDIN + u] = v;
    else if (u < kINTER + kCMD) xc1[r][u] = v;  // layout offset == u
    else xc2[r][kCMD + (u - (kINTER + kCMD))] = v;
  }
  for (int i = tid; i < kBCN; i += kNT) s_bc[i] = ws[kBCOff + i];
  if (tid < 64) s_fcb[tid] = fcb[tid];
  for (int i = tid; i < 64 * 64; i += kNT) {
    int m = i >> 6, o = i & 63;
    s_fcwT[i] = fcw[o * 64 + m];
  }
  __syncthreads();

  const float4* wp0 = (const float4*)ws;
  const float4* wp1 = (const float4*)ws + kW1OffQ;
  const float4* wp2 = (const float4*)ws + kW2OffQ;

  for (int t = 0; t < kT; ++t) {
    // stage x_t (kMT*kDIN == 512 elements)
    if (tid < kMT * kDIN) {
      int r = tid >> 7, d = tid & 127;
      xc0[r][d] = x[(size_t)(b0 + r) * (kT * kDIN) + t * kDIN + d];
    }
    __syncthreads();

    // ---- cell 0 ----
    if (tid < kC0)
      cell_matvec<kC0, kK40, kS0>(wp0, &xc0[0][0], &pacc[0][0], s_bc, tid);
    __syncthreads();
    if (tid < kINTER) {
#pragma unroll
      for (int r = 0; r < kMT; ++r) {
        float v = cfc_combine(pacc[r][tid],
                              pacc[r][tid + kINTER],
                              pacc[r][tid + 2 * kINTER]);
        xc1[r][tid] = v;          // input to cell 1
        xc0[r][kDIN + tid] = v;   // h0 for next step
      }
    }
    __syncthreads();

    // ---- cell 1 ----
    if (tid < kC1)
      cell_matvec<kC1, kK41, kS1>(wp1, &xc1[0][0], &pacc[0][0], s_bc + kC0, tid);
    __syncthreads();
    if (tid < kCMD) {
#pragma unroll
      for (int r = 0; r < kMT; ++r) {
        float v = cfc_combine(pacc[r][tid],
                              pacc[r][tid + kCMD],
                              pacc[r][tid + 2 * kCMD]);
        xc2[r][tid] = v;          // input to cell 2
        xc1[r][kINTER + tid] = v; // h1
      }
    }
    __syncthreads();

    // ---- cell 2 ----
    if (tid < kC2)
      cell_matvec<kC2, kK42, kS2>(wp2, &xc2[0][0], &pacc[0][0],
                                  s_bc + kC0 + kC1, tid);
    __syncthreads();
    if (tid < kMOTOR) {
#pragma unroll
      for (int r = 0; r < kMT; ++r) {
        float v = cfc_combine(pacc[r][tid],
                              pacc[r][tid + kMOTOR],
                              pacc[r][tid + 2 * kMOTOR]);
        xc2[r][kCMD + tid] = v;   // h2 == n2 == outs[t]
      }
    }
    __syncthreads();

    // ---- fc head: pred[b,t,o] = sum_m n2[m] * fc_w[o,m] + fc_b[o] ----
    if (tid < kMT * kOUT) {
      int r = tid >> 6, o = tid & 63;
      float acc = s_fcb[o];
#pragma unroll
      for (int m = 0; m < kMOTOR; ++m)
        acc = fmaf(xc2[r][kCMD + m], s_fcwT[m * 64 + o], acc);
      out[(size_t)(b0 + r) * (kT * kOUT) + (size_t)t * kOUT + o] = acc;
    }
    // next-iter x staging touches only xc0[:, :128]; its last reader was this
    // iteration's cell0 (pre-barrier) -> loop-top barrier is sufficient.
  }
  __syncthreads();

  // final hidden state
  const size_t hnoff = (size_t)kBatch * kT * kOUT;
  for (int i = tid; i < kMT * kUNITS; i += kNT) {
    int r = i >> 9, u = i & 511;
    float v;
    if (u < kINTER) v = xc0[r][kDIN + u];
    else if (u < kINTER + kCMD) v = xc1[r][u];
    else v = xc2[r][kCMD + (u - (kINTER + kCMD))];
    out[hnoff + (size_t)(b0 + r) * kUNITS + u] = v;
  }
}

// ---------------------------------------------------------------------------
extern "C" void kernel_launch(void* const* d_in, const int* in_sizes, int n_in,
                              void* d_out, int out_size, void* d_ws, size_t ws_size,
                              hipStream_t stream) {
  (void)in_sizes; (void)n_in; (void)out_size; (void)ws_size;
  const float* x = (const float*)d_in[0];
  const float* hidden = (const float*)d_in[1];
  const void* m0 = d_in[2];
  const void* m1 = d_in[3];
  const void* m2 = d_in[4];
  const float* f1w0 = (const float*)d_in[5];
  const float* f1b0 = (const float*)d_in[6];
  const float* f2w0 = (const float*)d_in[7];
  const float* f2b0 = (const float*)d_in[8];
  const float* taw0 = (const float*)d_in[9];
  const float* tab0 = (const float*)d_in[10];
  const float* tbw0 = (const float*)d_in[11];
  const float* tbb0 = (const float*)d_in[12];
  const float* f1w1 = (const float*)d_in[13];
  const float* f1b1 = (const float*)d_in[14];
  const float* f2w1 = (const float*)d_in[15];
  const float* f2b1 = (const float*)d_in[16];
  const float* taw1 = (const float*)d_in[17];
  const float* tab1 = (const float*)d_in[18];
  const float* tbw1 = (const float*)d_in[19];
  const float* tbb1 = (const float*)d_in[20];
  const float* f1w2 = (const float*)d_in[21];
  const float* f1b2 = (const float*)d_in[22];
  const float* f2w2 = (const float*)d_in[23];
  const float* f2b2 = (const float*)d_in[24];
  const float* taw2 = (const float*)d_in[25];
  const float* tab2 = (const float*)d_in[26];
  const float* tbw2 = (const float*)d_in[27];
  const float* tbb2 = (const float*)d_in[28];
  const float* fcw = (const float*)d_in[29];
  const float* fcb = (const float*)d_in[30];
  float* ws = (float*)d_ws;
  float* out = (float*)d_out;

  const int prep_items = kQ + kBCN;  // 154092
  prep_kernel<<<(prep_items + 255) / 256, 256, 0, stream>>>(
      m0, m1, m2,
      f1w0, f2w0, taw0, tbw0,
      f1w1, f2w1, taw1, tbw1,
      f1w2, f2w2, taw2, tbw2,
      f1b0, f2b0, tab0, tbb0,
      f1b1, f2b1, tab1, tbb1,
      f1b2, f2b2, tab2, tbb2,
      ws);

  ncp_main<<<kBatch / kMT, kNT, 0, stream>>>(x, hidden, ws, fcw, fcb, out);
}